// Round 1
// baseline (1959.674 us; speedup 1.0000x reference)
//
#include <hip/hip_runtime.h>
#include <cstdint>
#include <cstddef>

#define BB  32
#define FF  10
#define NBN 20
#define HH  128
#define GG  5

// Wavefront stage list: up to 20 active cells per stage, packed (r<<16)|(f<<8)|n.
struct StageList { int cnt; int cells[20]; };

__device__ __forceinline__ float sigm(float x) {
  return 1.f / (1.f + __expf(-x));
}
__device__ __forceinline__ float tanh_fast(float x) {
  // tanh(x) = sign(x) * (1 - e^{-2|x|}) / (1 + e^{-2|x|})  — overflow-safe
  float e = __expf(-2.f * fabsf(x));
  float t = (1.f - e) / (1.f + e);
  return copysignf(t, x);
}

// Boundary vectors: all are pure functions of the inputs (hoisted out of the recurrence).
// top_c  = mean_f cell, left_c = mean_n cell
// top_h0 = mean_f hid,  top_h1 = (gt + sum_f hid)/(F+1), left_h = mean_n hid (same both steps)
__global__ void precompute_kernel(
    const float* __restrict__ hid, const float* __restrict__ cell,
    const float* __restrict__ gt,
    float* __restrict__ top_c, float* __restrict__ left_c,
    float* __restrict__ top_h0, float* __restrict__ top_h1,
    float* __restrict__ left_h) {
  int idx = blockIdx.x * 256 + threadIdx.x;
  const int NTOP = BB * NBN * HH;   // 81920
  const int NLEFT = BB * FF * HH;   // 40960
  if (idx < NTOP) {
    int h = idx & (HH - 1);
    int n = (idx >> 7) % NBN;
    int b = idx / (HH * NBN);
    const float* hp = hid + (size_t)b * FF * NBN * HH + n * HH + h;
    const float* cp = cell + (size_t)b * FF * NBN * HH + n * HH + h;
    float sh = 0.f, sc = 0.f;
#pragma unroll
    for (int f = 0; f < FF; ++f) { sh += hp[f * NBN * HH]; sc += cp[f * NBN * HH]; }
    top_c[idx]  = sc * (1.f / FF);
    top_h0[idx] = sh * (1.f / FF);
    top_h1[idx] = (sh + gt[idx]) * (1.f / (FF + 1));
  } else if (idx < NTOP + NLEFT) {
    int j = idx - NTOP;
    int h = j & (HH - 1);
    int f = (j >> 7) % FF;
    int b = j / (HH * FF);
    const float* hp = hid + (size_t)b * FF * NBN * HH + f * NBN * HH + h;
    const float* cp = cell + (size_t)b * FF * NBN * HH + f * NBN * HH + h;
    float sh = 0.f, sc = 0.f;
#pragma unroll
    for (int n = 0; n < NBN; ++n) { sh += hp[n * HH]; sc += cp[n * HH]; }
    left_c[j] = sc * (1.f / NBN);
    left_h[j] = sh * (1.f / NBN);
  }
}

// One diagonal stage. Grid = cnt*4 blocks (4 batch-groups of 8 per cell), 640 threads.
// Thread t -> gate g = t>>7, output col c = t&127; accumulates 8 batches in registers.
__global__ __launch_bounds__(640)
void stage_kernel(const float* __restrict__ p,
                  const float* __restrict__ U,
                  const float* __restrict__ Wt,
                  const float* __restrict__ Ws,
                  const float* __restrict__ bias,
                  const float* __restrict__ top_c,
                  const float* __restrict__ left_c,
                  const float* __restrict__ top_h0,
                  const float* __restrict__ top_h1,
                  const float* __restrict__ left_h,
                  float* __restrict__ h0,
                  float* __restrict__ c0,
                  float* __restrict__ out_h,
                  float* __restrict__ out_c,
                  StageList sl) {
  __shared__ float zs[GG][HH][8];  // 20 KB gate-combine buffer

  const int cellIdx = blockIdx.x >> 2;
  const int bg = blockIdx.x & 3;
  const int packed = sl.cells[cellIdx];
  const int r = (packed >> 16) & 0xff;
  const int f = (packed >> 8) & 0xff;
  const int n = packed & 0xff;
  const int t = threadIdx.x;
  const int g = t >> 7;
  const int c = t & (HH - 1);
  const int b0 = bg * 8;

  const int BSTR = FF * NBN * HH;  // 25600 (batch stride of [B,F,NB,H])
  const int FSTR = NBN * HH;       // 2560
  const int cellofs = f * FSTR + n * HH;

  float* hout = r ? out_h : h0;
  float* cout = r ? out_c : c0;

  // x: step input (p for r=0, step-0 h for r=1)
  const float* xp = (r ? h0 : p) + cellofs;
  const int xbs = BSTR;
  // ht: row above (or precomputed top boundary)
  const float* hp; int hbs;
  if (f > 0) { hp = hout + cellofs - FSTR; hbs = BSTR; }
  else       { hp = (r ? top_h1 : top_h0) + n * HH; hbs = NBN * HH; }
  // h_left: col to the left (or precomputed left boundary)
  const float* lp; int lbs;
  if (n > 0) { lp = hout + cellofs - HH; lbs = BSTR; }
  else       { lp = left_h + f * HH; lbs = FF * HH; }

  // Per-cell weight blocks: U/Wt/Ws [R,F,NB,5,H,H], bias [R,F,NB,5,H]
  const size_t wofs = ((size_t)(r * FF + f) * NBN + n) * ((size_t)GG * HH * HH)
                    + (size_t)g * HH * HH + c;
  const float* wu = U + wofs;
  const float* wt = Wt + wofs;
  const float* wsm = Ws + wofs;
  const float bv = bias[((size_t)(r * FF + f) * NBN + n) * (GG * HH) + g * HH + c];

  float acc[8];
#pragma unroll
  for (int b = 0; b < 8; ++b) acc[b] = 0.f;

#pragma unroll 2
  for (int k = 0; k < HH; k += 4) {
    // weight column elements, coalesced across c (consecutive lanes)
    float wu0 = wu[(k + 0) * HH], wu1 = wu[(k + 1) * HH], wu2 = wu[(k + 2) * HH], wu3 = wu[(k + 3) * HH];
    float wt0 = wt[(k + 0) * HH], wt1 = wt[(k + 1) * HH], wt2 = wt[(k + 2) * HH], wt3 = wt[(k + 3) * HH];
    float ws0 = wsm[(k + 0) * HH], ws1 = wsm[(k + 1) * HH], ws2 = wsm[(k + 2) * HH], ws3 = wsm[(k + 3) * HH];
#pragma unroll
    for (int b = 0; b < 8; ++b) {
      // wave-uniform broadcast loads (same address across all lanes)
      const float4 xv = *(const float4*)(xp + (size_t)(b0 + b) * xbs + k);
      const float4 tv = *(const float4*)(hp + (size_t)(b0 + b) * hbs + k);
      const float4 lv = *(const float4*)(lp + (size_t)(b0 + b) * lbs + k);
      float a = acc[b];
      a = fmaf(xv.x, wu0, a); a = fmaf(xv.y, wu1, a); a = fmaf(xv.z, wu2, a); a = fmaf(xv.w, wu3, a);
      a = fmaf(tv.x, wt0, a); a = fmaf(tv.y, wt1, a); a = fmaf(tv.z, wt2, a); a = fmaf(tv.w, wt3, a);
      a = fmaf(lv.x, ws0, a); a = fmaf(lv.y, ws1, a); a = fmaf(lv.z, ws2, a); a = fmaf(lv.w, ws3, a);
      acc[b] = a;
    }
  }

#pragma unroll
  for (int b = 0; b < 8; ++b) zs[g][c][b] = acc[b] + bv;
  __syncthreads();

  if (t < HH) {  // one thread per output column combines the 5 gates
    const float* ctp; int ctbs;
    if (f > 0) { ctp = cout + cellofs - FSTR; ctbs = BSTR; }
    else       { ctp = top_c + n * HH; ctbs = NBN * HH; }
    const float* clp; int clbs;
    if (n > 0) { clp = cout + cellofs - HH; clbs = BSTR; }
    else       { clp = left_c + f * HH; clbs = FF * HH; }
#pragma unroll
    for (int b = 0; b < 8; ++b) {
      int bb = b0 + b;
      float zi = zs[0][t][b], zfs = zs[1][t][b], zft = zs[2][t][b];
      float zo = zs[3][t][b], zc = zs[4][t][b];
      float iv = sigm(zi), fsv = sigm(zfs), ftv = sigm(zft), ov = sigm(zo);
      float cn = tanh_fast(zc);
      float clv = clp[(size_t)bb * clbs + t];
      float ctv = ctp[(size_t)bb * ctbs + t];
      float cnew = fmaf(iv, cn, fmaf(fsv, clv, ftv * ctv));
      float hnew = ov * tanh_fast(cnew);
      hout[(size_t)bb * BSTR + cellofs + t] = hnew;
      cout[(size_t)bb * BSTR + cellofs + t] = cnew;
    }
  }
}

extern "C" void kernel_launch(void* const* d_in, const int* in_sizes, int n_in,
                              void* d_out, int out_size, void* d_ws, size_t ws_size,
                              hipStream_t stream) {
  const float* hid  = (const float*)d_in[0];  // hidden_states [B,F,NB,H]
  const float* cell = (const float*)d_in[1];  // cell_states   [B,F,NB,H]
  const float* gt   = (const float*)d_in[2];  // global_t_state [B,NB,H]
  // d_in[3] = global_s_state — unused for R=2 (only read when i>=2 in the reference)
  const float* p    = (const float*)d_in[4];  // p [B,F,NB,H]
  const float* U    = (const float*)d_in[5];  // [R,F,NB,5,H,H]
  const float* Wt   = (const float*)d_in[6];
  const float* Ws   = (const float*)d_in[7];
  const float* bias = (const float*)d_in[8];  // [R,F,NB,5,H]

  float* out_h = (float*)d_out;                               // h_int
  float* out_c = out_h + (size_t)BB * FF * NBN * HH;          // c_int

  // workspace carve (fp32): ~7.9 MB total
  float* w = (float*)d_ws;
  float* h0     = w; w += (size_t)BB * FF * NBN * HH;  // 819200
  float* c0     = w; w += (size_t)BB * FF * NBN * HH;  // 819200
  float* top_c  = w; w += (size_t)BB * NBN * HH;       // 81920
  float* left_c = w; w += (size_t)BB * FF * HH;        // 40960
  float* top_h0 = w; w += (size_t)BB * NBN * HH;       // 81920
  float* top_h1 = w; w += (size_t)BB * NBN * HH;       // 81920
  float* left_h = w; w += (size_t)BB * FF * HH;        // 40960

  const int pre_threads = BB * NBN * HH + BB * FF * HH;  // 122880
  hipLaunchKernelGGL(precompute_kernel, dim3((pre_threads + 255) / 256), dim3(256),
                     0, stream, hid, cell, gt, top_c, left_c, top_h0, top_h1, left_h);

  // 30 wavefront stages: r=0 cells at d=f+n, r=1 cells at d=f+n+1 (steps pipeline, offset 1)
  for (int d = 0; d < FF + NBN; ++d) {
    StageList sl; sl.cnt = 0;
    for (int r = 0; r < 2; ++r) {
      int dd = d - r;
      for (int f = 0; f < FF; ++f) {
        int n = dd - f;
        if (n >= 0 && n < NBN) sl.cells[sl.cnt++] = (r << 16) | (f << 8) | n;
      }
    }
    if (sl.cnt == 0) continue;
    hipLaunchKernelGGL(stage_kernel, dim3(sl.cnt * 4), dim3(640), 0, stream,
                       p, U, Wt, Ws, bias, top_c, left_c, top_h0, top_h1, left_h,
                       h0, c0, out_h, out_c, sl);
  }
}

// Round 2
// 1454.019 us; speedup vs baseline: 1.3478x; 1.3478x over previous
//
#include <hip/hip_runtime.h>
#include <cstdint>
#include <cstddef>

#define BB  32
#define FF  10
#define NBN 20
#define HH  128
#define GG  5
#define BSTR (FF*NBN*HH)   // 25600
#define FSTR (NBN*HH)      // 2560

struct StageList { int cnt; int cells[20]; };  // packed (r<<16)|(f<<8)|n

__device__ __forceinline__ float sigm(float x) {
  return 1.f / (1.f + __expf(-x));
}
__device__ __forceinline__ float tanh_fast(float x) {
  float e = __expf(-2.f * fabsf(x));
  float t = (1.f - e) / (1.f + e);
  return copysignf(t, x);
}

// Boundary vectors (pure functions of inputs).
__global__ void precompute_kernel(
    const float* __restrict__ hid, const float* __restrict__ cell,
    const float* __restrict__ gt,
    float* __restrict__ top_c, float* __restrict__ left_c,
    float* __restrict__ top_h0, float* __restrict__ top_h1,
    float* __restrict__ left_h) {
  int idx = blockIdx.x * 256 + threadIdx.x;
  const int NTOP = BB * NBN * HH;   // 81920
  const int NLEFT = BB * FF * HH;   // 40960
  if (idx < NTOP) {
    int h = idx & (HH - 1);
    int n = (idx >> 7) % NBN;
    int b = idx / (HH * NBN);
    const float* hp = hid + (size_t)b * BSTR + n * HH + h;
    const float* cp = cell + (size_t)b * BSTR + n * HH + h;
    float sh = 0.f, sc = 0.f;
#pragma unroll
    for (int f = 0; f < FF; ++f) { sh += hp[f * FSTR]; sc += cp[f * FSTR]; }
    top_c[idx]  = sc * (1.f / FF);
    top_h0[idx] = sh * (1.f / FF);
    top_h1[idx] = (sh + gt[idx]) * (1.f / (FF + 1));
  } else if (idx < NTOP + NLEFT) {
    int j = idx - NTOP;
    int h = j & (HH - 1);
    int f = (j >> 7) % FF;
    int b = j / (HH * FF);
    const float* hp = hid + (size_t)b * BSTR + f * FSTR + h;
    const float* cp = cell + (size_t)b * BSTR + f * FSTR + h;
    float sh = 0.f, sc = 0.f;
#pragma unroll
    for (int n = 0; n < NBN; ++n) { sh += hp[n * HH]; sc += cp[n * HH]; }
    left_c[j] = sc * (1.f / NBN);
    left_h[j] = sh * (1.f / NBN);
  }
}

// Z0[cell] = p . U[0,cell] + bias[0,cell]  — dependency-free, full parallelism.
// grid = 200*5 blocks, 512 threads. Thread: c = t&127, bq = t>>7 (8 batches).
__global__ __launch_bounds__(512)
void z0_kernel(const float* __restrict__ p, const float* __restrict__ U,
               const float* __restrict__ bias, float* __restrict__ Z) {
  __shared__ float xs[BB][HH];  // 16 KB
  const int cell = blockIdx.x / GG, g = blockIdx.x % GG;
  const int f = cell / NBN, n = cell % NBN;
  const int t = threadIdx.x;
  const int c = t & (HH - 1), bq = t >> 7, b0 = bq * 8;
  const int cellofs = f * FSTR + n * HH;

  for (int i = t; i < BB * HH; i += 512) {
    int b = i >> 7, k = i & (HH - 1);
    xs[b][k] = p[(size_t)b * BSTR + cellofs + k];
  }
  __syncthreads();

  const float* wup = U + (size_t)cell * (GG * HH * HH) + (size_t)g * HH * HH + c;
  const float bv = bias[(size_t)cell * (GG * HH) + g * HH + c];
  float acc[8];
#pragma unroll
  for (int b = 0; b < 8; ++b) acc[b] = bv;

#pragma unroll 2
  for (int kg = 0; kg < HH / 4; ++kg) {
    const int k = kg * 4;
    float u0 = wup[(k + 0) * HH], u1 = wup[(k + 1) * HH];
    float u2 = wup[(k + 2) * HH], u3 = wup[(k + 3) * HH];
#pragma unroll
    for (int b = 0; b < 8; ++b) {
      float4 xv = *(const float4*)&xs[b0 + b][k];
      acc[b] += xv.x * u0 + xv.y * u1 + xv.z * u2 + xv.w * u3;
    }
  }

  float* zp = Z + (size_t)cell * (BB * GG * HH) + g * HH + c;
#pragma unroll
  for (int b = 0; b < 8; ++b) zp[(size_t)(b0 + b) * (GG * HH)] = acc[b];
}

// Dependent GEMV for one stage. grid = cnt*5 blocks, 512 threads.
// r=0: Z[cell] += ht.Wt + hs.Ws  (Z holds p.U + bias already)
// r=1: Z[cell]  = h0.U + ht.Wt + hs.Ws + bias   (slot reuse is safe: r0 combine
//      of this cell ran last stage)
__global__ __launch_bounds__(512)
void gemv_stage(const float* __restrict__ U, const float* __restrict__ Wt,
                const float* __restrict__ Ws, const float* __restrict__ bias,
                const float* __restrict__ h0, const float* __restrict__ out_h,
                const float* __restrict__ top_h0, const float* __restrict__ top_h1,
                const float* __restrict__ left_h,
                float* __restrict__ Z, StageList sl) {
  __shared__ float hts[BB][HH];  // 16 KB
  __shared__ float hss[BB][HH];  // 16 KB
  __shared__ float xss[BB][HH];  // 16 KB (r=1 only)

  const int cellIdx = blockIdx.x / GG, g = blockIdx.x % GG;
  const int packed = sl.cells[cellIdx];
  const int r = (packed >> 16) & 0xff;
  const int f = (packed >> 8) & 0xff;
  const int n = packed & 0xff;
  const int t = threadIdx.x;
  const int c = t & (HH - 1), bq = t >> 7, b0 = bq * 8;
  const int cellofs = f * FSTR + n * HH;

  const float* hbase = r ? out_h : h0;
  const float* hp; int hbs;
  if (f > 0) { hp = hbase + cellofs - FSTR; hbs = BSTR; }
  else       { hp = (r ? top_h1 : top_h0) + n * HH; hbs = FSTR; }
  const float* lp; int lbs;
  if (n > 0) { lp = hbase + cellofs - HH; lbs = BSTR; }
  else       { lp = left_h + f * HH; lbs = FF * HH; }

  for (int i = t; i < BB * HH; i += 512) {
    int b = i >> 7, k = i & (HH - 1);
    hts[b][k] = hp[(size_t)b * hbs + k];
    hss[b][k] = lp[(size_t)b * lbs + k];
    if (r) xss[b][k] = h0[(size_t)b * BSTR + cellofs + k];
  }
  __syncthreads();

  const size_t wofs = ((size_t)(r * FF + f) * NBN + n) * (GG * HH * HH)
                    + (size_t)g * HH * HH + c;
  const float* wtp = Wt + wofs;
  const float* wsp = Ws + wofs;
  const float* wup = U + wofs;

  float acc[8];
  const float bv = r ? bias[(((size_t)(FF + f) * NBN + n) * GG + g) * HH + c] : 0.f;
#pragma unroll
  for (int b = 0; b < 8; ++b) acc[b] = bv;

  if (r) {
#pragma unroll 2
    for (int kg = 0; kg < HH / 4; ++kg) {
      const int k = kg * 4;
      float t0 = wtp[(k + 0) * HH], t1 = wtp[(k + 1) * HH], t2 = wtp[(k + 2) * HH], t3 = wtp[(k + 3) * HH];
      float s0 = wsp[(k + 0) * HH], s1 = wsp[(k + 1) * HH], s2 = wsp[(k + 2) * HH], s3 = wsp[(k + 3) * HH];
      float u0 = wup[(k + 0) * HH], u1 = wup[(k + 1) * HH], u2 = wup[(k + 2) * HH], u3 = wup[(k + 3) * HH];
#pragma unroll
      for (int b = 0; b < 8; ++b) {
        float4 hv = *(const float4*)&hts[b0 + b][k];
        float4 sv = *(const float4*)&hss[b0 + b][k];
        float4 xv = *(const float4*)&xss[b0 + b][k];
        float a = acc[b];
        a += hv.x * t0 + hv.y * t1 + hv.z * t2 + hv.w * t3;
        a += sv.x * s0 + sv.y * s1 + sv.z * s2 + sv.w * s3;
        a += xv.x * u0 + xv.y * u1 + xv.z * u2 + xv.w * u3;
        acc[b] = a;
      }
    }
  } else {
#pragma unroll 2
    for (int kg = 0; kg < HH / 4; ++kg) {
      const int k = kg * 4;
      float t0 = wtp[(k + 0) * HH], t1 = wtp[(k + 1) * HH], t2 = wtp[(k + 2) * HH], t3 = wtp[(k + 3) * HH];
      float s0 = wsp[(k + 0) * HH], s1 = wsp[(k + 1) * HH], s2 = wsp[(k + 2) * HH], s3 = wsp[(k + 3) * HH];
#pragma unroll
      for (int b = 0; b < 8; ++b) {
        float4 hv = *(const float4*)&hts[b0 + b][k];
        float4 sv = *(const float4*)&hss[b0 + b][k];
        float a = acc[b];
        a += hv.x * t0 + hv.y * t1 + hv.z * t2 + hv.w * t3;
        a += sv.x * s0 + sv.y * s1 + sv.z * s2 + sv.w * s3;
        acc[b] = a;
      }
    }
  }

  float* zp = Z + (size_t)(f * NBN + n) * (BB * GG * HH) + g * HH + c;
  if (r) {
#pragma unroll
    for (int b = 0; b < 8; ++b) zp[(size_t)(b0 + b) * (GG * HH)] = acc[b];
  } else {
#pragma unroll
    for (int b = 0; b < 8; ++b) zp[(size_t)(b0 + b) * (GG * HH)] += acc[b];
  }
}

// Gate combine for one stage. grid = cnt blocks, 256 threads.
__global__ __launch_bounds__(256)
void combine_stage(const float* __restrict__ Z,
                   const float* __restrict__ top_c, const float* __restrict__ left_c,
                   float* __restrict__ h0, float* __restrict__ c0,
                   float* __restrict__ out_h, float* __restrict__ out_c,
                   StageList sl) {
  const int packed = sl.cells[blockIdx.x];
  const int r = (packed >> 16) & 0xff;
  const int f = (packed >> 8) & 0xff;
  const int n = packed & 0xff;
  const int t = threadIdx.x;
  const int c = t & (HH - 1), bh = t >> 7;
  const int cellofs = f * FSTR + n * HH;

  float* hout = r ? out_h : h0;
  float* cout = r ? out_c : c0;
  const float* ctp; int ctbs;
  if (f > 0) { ctp = cout + cellofs - FSTR; ctbs = BSTR; }
  else       { ctp = top_c + n * HH; ctbs = FSTR; }
  const float* clp; int clbs;
  if (n > 0) { clp = cout + cellofs - HH; clbs = BSTR; }
  else       { clp = left_c + f * HH; clbs = FF * HH; }

  const float* zp = Z + (size_t)(f * NBN + n) * (BB * GG * HH) + c;
#pragma unroll
  for (int i = 0; i < 16; ++i) {
    const int b = bh * 16 + i;
    const float* zb = zp + (size_t)b * (GG * HH);
    float zi = zb[0], zfs = zb[HH], zft = zb[2 * HH], zo = zb[3 * HH], zc = zb[4 * HH];
    float iv = sigm(zi), fsv = sigm(zfs), ftv = sigm(zft), ov = sigm(zo);
    float cn = tanh_fast(zc);
    float clv = clp[(size_t)b * clbs + c];
    float ctv = ctp[(size_t)b * ctbs + c];
    float cnew = fmaf(iv, cn, fmaf(fsv, clv, ftv * ctv));
    float hnew = ov * tanh_fast(cnew);
    hout[(size_t)b * BSTR + cellofs + c] = hnew;
    cout[(size_t)b * BSTR + cellofs + c] = cnew;
  }
}

extern "C" void kernel_launch(void* const* d_in, const int* in_sizes, int n_in,
                              void* d_out, int out_size, void* d_ws, size_t ws_size,
                              hipStream_t stream) {
  const float* hid  = (const float*)d_in[0];
  const float* cell = (const float*)d_in[1];
  const float* gt   = (const float*)d_in[2];
  // d_in[3] = global_s_state — dead for R=2
  const float* p    = (const float*)d_in[4];
  const float* U    = (const float*)d_in[5];
  const float* Wt   = (const float*)d_in[6];
  const float* Ws   = (const float*)d_in[7];
  const float* bias = (const float*)d_in[8];

  float* out_h = (float*)d_out;
  float* out_c = out_h + (size_t)BB * BSTR;

  // workspace carve (~24.3 MB fp32)
  float* w = (float*)d_ws;
  float* h0     = w; w += (size_t)BB * BSTR;        // 819200
  float* c0     = w; w += (size_t)BB * BSTR;        // 819200
  float* top_c  = w; w += (size_t)BB * NBN * HH;    // 81920
  float* left_c = w; w += (size_t)BB * FF * HH;     // 40960
  float* top_h0 = w; w += (size_t)BB * NBN * HH;
  float* top_h1 = w; w += (size_t)BB * NBN * HH;
  float* left_h = w; w += (size_t)BB * FF * HH;
  float* Z      = w; w += (size_t)FF * NBN * BB * GG * HH;  // 4,096,000 (16.4 MB)

  const int pre_threads = BB * NBN * HH + BB * FF * HH;
  hipLaunchKernelGGL(precompute_kernel, dim3((pre_threads + 255) / 256), dim3(256),
                     0, stream, hid, cell, gt, top_c, left_c, top_h0, top_h1, left_h);

  hipLaunchKernelGGL(z0_kernel, dim3(FF * NBN * GG), dim3(512), 0, stream,
                     p, U, bias, Z);

  for (int d = 0; d < FF + NBN; ++d) {
    StageList sl; sl.cnt = 0;
    for (int r = 0; r < 2; ++r) {
      int dd = d - r;
      for (int f = 0; f < FF; ++f) {
        int n = dd - f;
        if (n >= 0 && n < NBN) sl.cells[sl.cnt++] = (r << 16) | (f << 8) | n;
      }
    }
    if (sl.cnt == 0) continue;
    hipLaunchKernelGGL(gemv_stage, dim3(sl.cnt * GG), dim3(512), 0, stream,
                       U, Wt, Ws, bias, h0, out_h, top_h0, top_h1, left_h, Z, sl);
    hipLaunchKernelGGL(combine_stage, dim3(sl.cnt), dim3(256), 0, stream,
                       Z, top_c, left_c, h0, c0, out_h, out_c, sl);
  }
}